// Round 3
// baseline (244.030 us; speedup 1.0000x reference)
//
#include <hip/hip_runtime.h>

typedef __attribute__((ext_vector_type(8))) __bf16 bf16x8;
typedef __attribute__((ext_vector_type(4))) float f32x4;

constexpr int Bsz   = 128;
constexpr int EE    = 200;
constexpr int EP    = 256;   // padded embed dim
constexpr int KP    = 224;   // padded K for gemm2/3 (covers 200)
constexpr int NMASK = 192;
constexpr int NVIS  = 64;
constexpr int PE    = 768;
constexpr int M1    = Bsz * NVIS;   // 8192
constexpr int M3    = M1 + NMASK;   // 8384
constexpr long IMG_ELEMS = (long)Bsz * 3 * 256 * 256;

// ---------------------------------------------------------------------------
// Prep: pad/convert weights to bf16 (B matrices in n-major [n][k] layout),
// pad pos/biases, write masked rows of `full`, emit masked_idx output.
// ---------------------------------------------------------------------------
__global__ __launch_bounds__(256) void k_prep(
    const float* __restrict__ pos, const float* __restrict__ wflat,
    const float* __restrict__ Wenc, const float* __restrict__ Wdec,
    const float* __restrict__ conv_b, const float* __restrict__ b_enc,
    const float* __restrict__ mask_token, const int* __restrict__ perm,
    float* __restrict__ posP, __bf16* __restrict__ W1t,
    __bf16* __restrict__ W2t, __bf16* __restrict__ W3t,
    float* __restrict__ cbp, float* __restrict__ bep,
    __bf16* __restrict__ full, float* __restrict__ out_idx)
{
    int blk = blockIdx.x, t = threadIdx.x;
    if (blk < 256) {                       // posP [256][256]
        posP[blk * 256 + t] = (t < EE) ? pos[blk * EE + t] : 0.f;
        return;
    }
    blk -= 256;
    if (blk < 768) {                       // W1t [256][768] (f-major, zero pad f>=200)
        int e = blk / 3, k = (blk % 3) * 256 + t;
        W1t[e * 768 + k] = (e < EE) ? (__bf16)wflat[e * 768 + k] : (__bf16)0.f;
        return;
    }
    blk -= 768;
    if (blk < 256) {                       // W2t [256][224] = Wenc^T padded
        if (t < KP) W2t[blk * KP + t] =
            (blk < EE && t < EE) ? (__bf16)Wenc[t * EE + blk] : (__bf16)0.f;
        return;
    }
    blk -= 256;
    if (blk < 768) {                       // W3t [768][224] = Wdec^T padded
        if (t < KP) W3t[blk * KP + t] =
            (t < EE) ? (__bf16)Wdec[t * PE + blk] : (__bf16)0.f;
        return;
    }
    blk -= 768;
    if (blk < NMASK) {                     // masked rows of full: mask_token + pos
        int n = perm[blk];
        full[(M1 + blk) * EP + t] =
            (t < EE) ? (__bf16)(mask_token[t] + pos[n * EE + t]) : (__bf16)0.f;
        return;
    }
    cbp[t] = (t < EE) ? conv_b[t] : 0.f;
    bep[t] = (t < EE) ? b_enc[t] : 0.f;
    if (t < NMASK) out_idx[t] = (float)perm[t];
}

// ---------------------------------------------------------------------------
// Fused encoder: per block, 32 visible rows.
// Phase 1 (gemm1): visible[32][256] = patch . W1t^T + cb + pos, kept in LDS.
//   A-frags gathered straight from x (fp32->bf16), B-frags direct from L2.
// Phase 2 (gemm2): full[32][256] = visible . W2t^T + be + pos  -> global bf16.
// One barrier total.
// ---------------------------------------------------------------------------
__global__ __launch_bounds__(256) void k_enc(
    const float* __restrict__ x, const __bf16* __restrict__ W1t,
    const __bf16* __restrict__ W2t, const float* __restrict__ cbp,
    const float* __restrict__ bep, const float* __restrict__ posP,
    const int* __restrict__ perm, __bf16* __restrict__ full)
{
    __shared__ __bf16 visLds[32][264];
    const int t = threadIdx.x;
    const int w = t >> 6;              // wave 0..3, owns cols w*64..w*64+63
    const int lane = t & 63;
    const int quad = lane >> 4, lid = lane & 15;
    const int m0 = blockIdx.x * 32;

    // A-row gather bases (rows m0+i*16+lid)
    int abase[2], nrow[2];
    #pragma unroll
    for (int i = 0; i < 2; ++i) {
        int m = m0 + i * 16 + lid;
        int n = perm[NMASK + (m & 63)];
        nrow[i] = n;
        abase[i] = (m >> 6) * 196608 + (n >> 4) * 4096 + (n & 15) * 16;
    }

    // ---- phase 1: gemm1, no barriers ----
    f32x4 acc[2][4] = {};
    for (int k0 = 0; k0 < PE; k0 += 32) {
        int k = k0 + quad * 8;
        int c = k >> 8, py = (k >> 4) & 15, px = k & 15;
        int aoff = c * 65536 + py * 256 + px;
        bf16x8 af[2];
        #pragma unroll
        for (int i = 0; i < 2; ++i) {
            const float* ap = x + abase[i] + aoff;
            float4 a0 = *(const float4*)ap;
            float4 a1 = *(const float4*)(ap + 4);
            af[i][0] = (__bf16)a0.x; af[i][1] = (__bf16)a0.y;
            af[i][2] = (__bf16)a0.z; af[i][3] = (__bf16)a0.w;
            af[i][4] = (__bf16)a1.x; af[i][5] = (__bf16)a1.y;
            af[i][6] = (__bf16)a1.z; af[i][7] = (__bf16)a1.w;
        }
        #pragma unroll
        for (int j = 0; j < 4; ++j) {
            int f = w * 64 + j * 16 + lid;
            bf16x8 bv = *(const bf16x8*)&W1t[f * 768 + k];
            acc[0][j] = __builtin_amdgcn_mfma_f32_16x16x32_bf16(af[0], bv, acc[0][j], 0, 0, 0);
            acc[1][j] = __builtin_amdgcn_mfma_f32_16x16x32_bf16(af[1], bv, acc[1][j], 0, 0, 0);
        }
    }

    // stash visible (+bias+pos) into LDS
    #pragma unroll
    for (int i = 0; i < 2; ++i) {
        #pragma unroll
        for (int j = 0; j < 4; ++j) {
            int f = w * 64 + j * 16 + lid;
            float bias = cbp[f];
            #pragma unroll
            for (int r = 0; r < 4; ++r) {
                int lm = i * 16 + quad * 4 + r;
                int n = perm[NMASK + ((m0 + lm) & 63)];
                visLds[lm][f] = (__bf16)(acc[i][j][r] + bias + posP[n * 256 + f]);
            }
        }
    }
    __syncthreads();

    // ---- phase 2: gemm2, A from LDS, B direct from L2 ----
    f32x4 acc2[2][4] = {};
    for (int k0 = 0; k0 < KP; k0 += 32) {
        int k = k0 + quad * 8;
        bf16x8 av[2];
        #pragma unroll
        for (int i = 0; i < 2; ++i)
            av[i] = *(const bf16x8*)&visLds[i * 16 + lid][k];
        #pragma unroll
        for (int j = 0; j < 4; ++j) {
            int f = w * 64 + j * 16 + lid;
            bf16x8 bv = *(const bf16x8*)&W2t[f * KP + k];
            acc2[0][j] = __builtin_amdgcn_mfma_f32_16x16x32_bf16(av[0], bv, acc2[0][j], 0, 0, 0);
            acc2[1][j] = __builtin_amdgcn_mfma_f32_16x16x32_bf16(av[1], bv, acc2[1][j], 0, 0, 0);
        }
    }

    #pragma unroll
    for (int i = 0; i < 2; ++i) {
        #pragma unroll
        for (int j = 0; j < 4; ++j) {
            int f = w * 64 + j * 16 + lid;
            float bias = bep[f];
            #pragma unroll
            for (int r = 0; r < 4; ++r) {
                int lm = i * 16 + quad * 4 + r;
                int m = m0 + lm;
                int n = perm[NMASK + (m & 63)];
                full[m * EP + f] = (__bf16)(acc2[i][j][r] + bias + posP[n * 256 + f]);
            }
        }
    }
}

// ---------------------------------------------------------------------------
// Decoder: dec[m][p] = full[m] . W3t[p] + bd[p].  M=8384(->8448) K=224 N=768.
// No LDS, no barriers: A and B fragments direct from L2. 128x128 block tile,
// each wave 64x64 (16 MFMA/k-step). Visible rows -> img, masked -> dec_masked.
// ---------------------------------------------------------------------------
__global__ __launch_bounds__(256) void k_dec(
    const __bf16* __restrict__ full, const __bf16* __restrict__ W3t,
    const float* __restrict__ bdec, const int* __restrict__ perm,
    float* __restrict__ img, float* __restrict__ dec_masked)
{
    const int t = threadIdx.x;
    const int w = t >> 6, lane = t & 63;
    const int wr = w >> 1, wc = w & 1;
    const int quad = lane >> 4, lid = lane & 15;
    const int m0 = blockIdx.y * 128, e0 = blockIdx.x * 128;

    int mrow[4];
    #pragma unroll
    for (int i = 0; i < 4; ++i) {
        int m = m0 + wr * 64 + i * 16 + lid;
        mrow[i] = (m < M3) ? m : (M3 - 1);   // clamp OOB reads
    }

    f32x4 acc[4][4] = {};
    for (int k0 = 0; k0 < KP; k0 += 32) {
        int k = k0 + quad * 8;
        bf16x8 av[4], bv[4];
        #pragma unroll
        for (int i = 0; i < 4; ++i)
            av[i] = *(const bf16x8*)&full[mrow[i] * EP + k];
        #pragma unroll
        for (int j = 0; j < 4; ++j) {
            int f = e0 + wc * 64 + j * 16 + lid;
            bv[j] = *(const bf16x8*)&W3t[f * KP + k];
        }
        #pragma unroll
        for (int i = 0; i < 4; ++i)
            #pragma unroll
            for (int j = 0; j < 4; ++j)
                acc[i][j] = __builtin_amdgcn_mfma_f32_16x16x32_bf16(av[i], bv[j], acc[i][j], 0, 0, 0);
    }

    #pragma unroll
    for (int i = 0; i < 4; ++i) {
        int mb = m0 + wr * 64 + i * 16 + quad * 4;
        #pragma unroll
        for (int j = 0; j < 4; ++j) {
            int e = e0 + wc * 64 + j * 16 + lid;
            int c = e >> 8, py = (e >> 4) & 15, px = e & 15;
            float bias = bdec[e];
            #pragma unroll
            for (int r = 0; r < 4; ++r) {
                int m = mb + r;
                float v = acc[i][j][r] + bias;
                if (m < M1) {
                    int b = m >> 6;
                    int n = perm[NMASK + (m & 63)];
                    img[(long)(b * 3 + c) * 65536 + ((n >> 4) * 16 + py) * 256
                        + (n & 15) * 16 + px] = v;
                } else if (m < M3) {
                    dec_masked[(m - M1) * PE + e] = v;
                }
            }
        }
    }
}

// ---------------------------------------------------------------------------
// Broadcast masked decoder rows (batch-independent) to all images.
// ---------------------------------------------------------------------------
__global__ __launch_bounds__(192) void k_foldmask(
    const float* __restrict__ dec_masked, const int* __restrict__ perm,
    float* __restrict__ img)
{
    const int i = blockIdx.x;      // masked slot 0..191
    const int b = blockIdx.y;      // batch
    const int n = perm[i];
    const int t = threadIdx.x;
    float4 v = *(const float4*)&dec_masked[i * PE + t * 4];
    int p = t * 4;
    int c = p >> 8, py = (p >> 4) & 15, px = p & 15;
    *(float4*)&img[(long)(b * 3 + c) * 65536 + ((n >> 4) * 16 + py) * 256
                   + (n & 15) * 16 + px] = v;
}

// ---------------------------------------------------------------------------
extern "C" void kernel_launch(void* const* d_in, const int* in_sizes, int n_in,
                              void* d_out, int out_size, void* d_ws, size_t ws_size,
                              hipStream_t stream)
{
    const float* x          = (const float*)d_in[0];
    const float* conv_w     = (const float*)d_in[1];
    const float* conv_b     = (const float*)d_in[2];
    const float* pos        = (const float*)d_in[3];
    const float* mask_token = (const float*)d_in[4];
    const float* W_enc      = (const float*)d_in[5];
    const float* b_enc      = (const float*)d_in[6];
    const float* W_dec      = (const float*)d_in[7];
    const float* b_dec      = (const float*)d_in[8];
    const int*   perm       = (const int*)d_in[9];
    float* out = (float*)d_out;

    __bf16* full = (__bf16*)d_ws;                       // M3*256
    __bf16* W1t  = full + M3 * EP;                      // 256*768
    __bf16* W2t  = W1t + 256 * 768;                     // 256*224
    __bf16* W3t  = W2t + 256 * KP;                      // 768*224
    float*  posP = (float*)(W3t + 768 * KP);            // 256*256
    float*  cbp  = posP + 256 * 256;                    // 256
    float*  bep  = cbp + 256;                           // 256
    float*  decm = bep + 256;                           // 192*768

    k_prep<<<256 + 768 + 256 + 768 + NMASK + 1, 256, 0, stream>>>(
        pos, conv_w, W_enc, W_dec, conv_b, b_enc, mask_token, perm,
        posP, W1t, W2t, W3t, cbp, bep, full, out + IMG_ELEMS);
    k_enc<<<256, 256, 0, stream>>>(x, W1t, W2t, cbp, bep, posP, perm, full);
    k_dec<<<dim3(6, 66), 256, 0, stream>>>(full, W3t, b_dec, perm, out, decm);
    k_foldmask<<<dim3(NMASK, Bsz), 192, 0, stream>>>(decm, perm, out);
}